// Round 11
// baseline (176.537 us; speedup 1.0000x reference)
//
#include <hip/hip_runtime.h>
#include <math.h>

#define TT 1024   // tokens
#define HH 1024   // hidden
#define MM 512    // moe intermediate
#define NE 16     // routed experts (blockIdx.z == NE -> shared expert)
// TOP_K = 2, SCALE = 2.5, NORM_TOPK = true

typedef _Float16 f16;
typedef _Float16 f16x8 __attribute__((ext_vector_type(8)));
typedef float f32x4 __attribute__((ext_vector_type(4)));

// async global->LDS: 16B/lane, dest = wave-uniform base + lane*16 (linear)
#define GLL(g, l) __builtin_amdgcn_global_load_lds(                         \
    (const __attribute__((address_space(1))) void*)(g),                     \
    (__attribute__((address_space(3))) void*)(l), 16, 0, 0)
#define SB() __builtin_amdgcn_sched_barrier(0)
#define WAITVM(N) { SB(); asm volatile("s_waitcnt vmcnt(" #N ")"); SB(); }
#define BARRIER() __builtin_amdgcn_s_barrier()

// ---------------- router ----------------
__global__ __launch_bounds__(256) void router_k(
    const float* __restrict__ x, const float* __restrict__ gate_w,
    int* __restrict__ counts, int* __restrict__ token_list, float* __restrict__ weight_list)
{
    const int wave = threadIdx.x >> 6;
    const int lane = threadIdx.x & 63;
    const int t = (blockIdx.x << 2) + wave;
    const float* xr = x + (size_t)t * HH;
    float xv[16];
#pragma unroll
    for (int i = 0; i < 16; ++i) xv[i] = xr[lane + (i << 6)];
    float sc[NE];
#pragma unroll
    for (int e = 0; e < NE; ++e) {
        const float* gr = gate_w + e * HH;
        float acc = 0.f;
#pragma unroll
        for (int i = 0; i < 16; ++i) acc = fmaf(xv[i], gr[lane + (i << 6)], acc);
#pragma unroll
        for (int off = 32; off > 0; off >>= 1) acc += __shfl_down(acc, off, 64);
        sc[e] = acc;   // valid on lane 0
    }
    if (lane == 0) {
        float l1 = -1e30f, l2 = -1e30f; int i1 = 0, i2 = 0;
#pragma unroll
        for (int e = 0; e < NE; ++e) {
            float v = sc[e];
            if (v > l1) { l2 = l1; i2 = i1; l1 = v; i1 = e; }
            else if (v > l2) { l2 = v; i2 = e; }
        }
        float w1 = 1.f / (1.f + __expf(-l1));
        float w2 = 1.f / (1.f + __expf(-l2));
        const float inv = 2.5f / (w1 + w2 + 1e-20f);
        w1 *= inv; w2 *= inv;
        int s1 = atomicAdd(&counts[i1], 1);
        token_list[i1 * TT + s1] = t;
        weight_list[i1 * TT + s1] = w1;
        int s2 = atomicAdd(&counts[i2], 1);
        token_list[i2 * TT + s2] = t;
        weight_list[i2 * TT + s2] = w2;
    }
}

__global__ void prefix_k(const int* __restrict__ counts, int* __restrict__ offs)
{
    if (threadIdx.x == 0 && blockIdx.x == 0) {
        int acc = 0;
#pragma unroll
        for (int e = 0; e < NE; ++e) { offs[e] = acc; acc += counts[e]; }
        offs[NE] = acc;
    }
}

// ================= fused gate/up =================
// grid = (MM/32, 4 chunks of 256 rows, NE+1). One block streams its expert's
// [1024][32] Wg+Wu panels ONCE through triple-buffered LDS (GLL, counted vmcnt,
// 1 barrier/phase). A (x rows, L2-resident) direct to registers, issued BEFORE
// the GLL group so A-dependency waits never drain the prefetch FIFO.
// Accumulators for up to 4 m-tiles live in registers across the K loop.
// B LDS [64][32] stored with col ^= ((k>>3)&1)<<4  -> frag reads 2-way (free).

#define GU_ISSUE(K0, BG, BU) {                                              \
    _Pragma("unroll") for (int j = 0; j < 2; ++j) {                         \
        GLL(pbg[j] + (size_t)(K0) * MM, &BG[(w << 4) + (j << 3)][0]);       \
        GLL(pbu[j] + (size_t)(K0) * MM, &BU[(w << 4) + (j << 3)][0]); } }

#define GU_PH(T, VC, BGc, BUc, BGi, BUi) {                                  \
    WAITVM(VC)                                                              \
    BARRIER();                                                              \
    float4 alo[4][2], ahi[4][2];                                            \
    _Pragma("unroll") for (int mt = 0; mt < 4; ++mt) if (mact[mt])          \
      _Pragma("unroll") for (int h = 0; h < 2; ++h) {                       \
        const float* ap = pa[mt] + ((T) << 6) + (h << 5);                   \
        alo[mt][h] = *(const float4*)ap; ahi[mt][h] = *(const float4*)(ap + 4); } \
    SB();                                                                   \
    if ((T) + 2 < 16) { GU_ISSUE(((T) + 2) << 6, BGi, BUi) }                \
    SB();                                                                   \
    _Pragma("unroll") for (int h = 0; h < 2; ++h) {                         \
      const int kb = (h << 5) + (lg << 3);                                  \
      f16x8 bg[2], bu[2];                                                   \
      _Pragma("unroll") for (int fj = 0; fj < 2; ++fj) {                    \
        const int bc = ((fj << 4) + lm) ^ ((lg & 1) << 4);                  \
        _Pragma("unroll") for (int jj = 0; jj < 8; ++jj) {                  \
          bg[fj][jj] = (f16)BGc[kb + jj][bc];                               \
          bu[fj][jj] = (f16)BUc[kb + jj][bc]; } }                           \
      _Pragma("unroll") for (int mt = 0; mt < 4; ++mt) if (mact[mt]) {      \
        float4 lo = alo[mt][h], hi = ahi[mt][h];                            \
        f16x8 av = {(f16)lo.x,(f16)lo.y,(f16)lo.z,(f16)lo.w,                \
                    (f16)hi.x,(f16)hi.y,(f16)hi.z,(f16)hi.w};               \
        _Pragma("unroll") for (int fj = 0; fj < 2; ++fj) {                  \
          accg[mt][fj] = __builtin_amdgcn_mfma_f32_16x16x32_f16(av, bg[fj], accg[mt][fj], 0, 0, 0); \
          accu[mt][fj] = __builtin_amdgcn_mfma_f32_16x16x32_f16(av, bu[fj], accu[mt][fj], 0, 0, 0); } } } }

__global__ __launch_bounds__(256) void gu_k(
    const float* __restrict__ x,
    const float* __restrict__ w_gate, const float* __restrict__ w_up,
    const float* __restrict__ ws_gate, const float* __restrict__ ws_up,
    const int* __restrict__ counts, const int* __restrict__ offs,
    const int* __restrict__ token_list, f16* __restrict__ rinter)
{
    const int e = blockIdx.z;
    int cnt, slot0;
    const float *wgp, *wup;
    if (e < NE) {
        cnt = counts[e]; slot0 = offs[e];
        wgp = w_gate + (size_t)e * HH * MM;
        wup = w_up   + (size_t)e * HH * MM;
    } else {
        cnt = TT; slot0 = 2 * TT;
        wgp = ws_gate; wup = ws_up;
    }
    const int rbase = blockIdx.y << 8;          // 256-row chunk
    if (rbase >= cnt) return;
    const int n0 = blockIdx.x << 5;

    __shared__ float Bg0[64][32], Bu0[64][32];
    __shared__ float Bg1[64][32], Bu1[64][32];
    __shared__ float Bg2[64][32], Bu2[64][32];
    __shared__ int toks[256];

    const int tid = threadIdx.x;
    {
        int i = rbase + tid; if (i >= cnt) i = cnt - 1;
        toks[tid] = (e < NE) ? token_list[e * TT + i] : i;
    }
    __syncthreads();

    const int w = tid >> 6, lane = tid & 63;
    const int lm = lane & 15, lg = lane >> 4;

    // B staging: wave w covers rows [16w,16w+16) of each matrix, 2 GLL each.
    const float* pbg[2]; const float* pbu[2];
#pragma unroll
    for (int j = 0; j < 2; ++j) {
        int r  = (w << 4) + (j << 3) + (lane >> 3);
        int cs = ((lane & 7) << 2) ^ (((r >> 3) & 1) << 4);   // pre-swizzled src col
        pbg[j] = wgp + (size_t)r * MM + n0 + cs;
        pbu[j] = wup + (size_t)r * MM + n0 + cs;
    }

    const bool mact[4] = { true, rbase + 64 < cnt, rbase + 128 < cnt, rbase + 192 < cnt };
    const float* pa[4];
#pragma unroll
    for (int mt = 0; mt < 4; ++mt) {
        int li = (mt << 6) + (w << 4) + lm;                   // 0..255 within chunk
        pa[mt] = x + (size_t)toks[li] * HH + (lg << 3);
    }

    f32x4 accg[4][2] = {}, accu[4][2] = {};

    GU_ISSUE(0,  Bg0, Bu0)
    GU_ISSUE(64, Bg1, Bu1)

    GU_PH(0, 4, Bg0, Bu0, Bg2, Bu2)  GU_PH(1, 4, Bg1, Bu1, Bg0, Bu0)
    GU_PH(2, 4, Bg2, Bu2, Bg1, Bu1)  GU_PH(3, 4, Bg0, Bu0, Bg2, Bu2)
    GU_PH(4, 4, Bg1, Bu1, Bg0, Bu0)  GU_PH(5, 4, Bg2, Bu2, Bg1, Bu1)
    GU_PH(6, 4, Bg0, Bu0, Bg2, Bu2)  GU_PH(7, 4, Bg1, Bu1, Bg0, Bu0)
    GU_PH(8, 4, Bg2, Bu2, Bg1, Bu1)  GU_PH(9, 4, Bg0, Bu0, Bg2, Bu2)
    GU_PH(10, 4, Bg1, Bu1, Bg0, Bu0) GU_PH(11, 4, Bg2, Bu2, Bg1, Bu1)
    GU_PH(12, 4, Bg0, Bu0, Bg2, Bu2) GU_PH(13, 4, Bg1, Bu1, Bg0, Bu0)
    GU_PH(14, 4, Bg2, Bu2, Bg0, Bu0) GU_PH(15, 0, Bg0, Bu0, Bg0, Bu0)

    // epilogue: silu(g)*u -> f16; C/D: col=lane&15, row=(lane>>4)*4+reg
#pragma unroll
    for (int mt = 0; mt < 4; ++mt) if (mact[mt])
#pragma unroll
        for (int fj = 0; fj < 2; ++fj)
#pragma unroll
            for (int rr = 0; rr < 4; ++rr) {
                int row = rbase + (mt << 6) + (w << 4) + (lg << 2) + rr;
                if (row < cnt) {
                    float g = accg[mt][fj][rr], u = accu[mt][fj][rr];
                    float s = g / (1.f + __expf(-g));
                    rinter[(size_t)(slot0 + row) * MM + n0 + (fj << 4) + lm] = (f16)(s * u);
                }
            }
}

// ================= down: out[token] += weight * (rinter @ Wd) =================
// grid = (HH/32, 4, NE+1). Same persistent-panel structure; A = rinter (f16,
// L2-resident, contiguous slots) direct to registers; B panel [512][32] GLL'd.

#define DN_ISSUE(K0, BD) {                                                  \
    _Pragma("unroll") for (int j = 0; j < 2; ++j)                           \
        GLL(pbd[j] + (size_t)(K0) * HH, &BD[(w << 4) + (j << 3)][0]); }

#define DN_PH(T, VC, BDc, BDi) {                                            \
    WAITVM(VC)                                                              \
    BARRIER();                                                              \
    f16x8 av[4][2];                                                         \
    _Pragma("unroll") for (int mt = 0; mt < 4; ++mt) if (mact[mt])          \
      _Pragma("unroll") for (int h = 0; h < 2; ++h)                         \
        av[mt][h] = *(const f16x8*)(pa[mt] + ((T) << 6) + (h << 5));        \
    SB();                                                                   \
    if ((T) + 2 < 8) { DN_ISSUE(((T) + 2) << 6, BDi) }                      \
    SB();                                                                   \
    _Pragma("unroll") for (int h = 0; h < 2; ++h) {                         \
      const int kb = (h << 5) + (lg << 3);                                  \
      f16x8 bd[2];                                                          \
      _Pragma("unroll") for (int fj = 0; fj < 2; ++fj) {                    \
        const int bc = ((fj << 4) + lm) ^ ((lg & 1) << 4);                  \
        _Pragma("unroll") for (int jj = 0; jj < 8; ++jj)                    \
          bd[fj][jj] = (f16)BDc[kb + jj][bc]; }                             \
      _Pragma("unroll") for (int mt = 0; mt < 4; ++mt) if (mact[mt])        \
        _Pragma("unroll") for (int fj = 0; fj < 2; ++fj)                    \
          acc[mt][fj] = __builtin_amdgcn_mfma_f32_16x16x32_f16(av[mt][h], bd[fj], acc[mt][fj], 0, 0, 0); } }

__global__ __launch_bounds__(256) void down_k(
    const f16* __restrict__ rinter,
    const float* __restrict__ w_down, const float* __restrict__ ws_down,
    const int* __restrict__ counts, const int* __restrict__ offs,
    const int* __restrict__ token_list, const float* __restrict__ weight_list,
    float* __restrict__ out)
{
    const int e = blockIdx.z;
    int cnt, slot0; const float* wdp;
    if (e < NE) { cnt = counts[e]; slot0 = offs[e]; wdp = w_down + (size_t)e * MM * HH; }
    else        { cnt = TT; slot0 = 2 * TT; wdp = ws_down; }
    const int rbase = blockIdx.y << 8;
    if (rbase >= cnt) return;
    const int n0 = blockIdx.x << 5;   // of HH

    __shared__ float Bd0[64][32], Bd1[64][32], Bd2[64][32];

    const int tid = threadIdx.x;
    const int w = tid >> 6, lane = tid & 63;
    const int lm = lane & 15, lg = lane >> 4;

    const float* pbd[2];
#pragma unroll
    for (int j = 0; j < 2; ++j) {
        int r  = (w << 4) + (j << 3) + (lane >> 3);
        int cs = ((lane & 7) << 2) ^ (((r >> 3) & 1) << 4);
        pbd[j] = wdp + (size_t)r * HH + n0 + cs;
    }

    const bool mact[4] = { true, rbase + 64 < cnt, rbase + 128 < cnt, rbase + 192 < cnt };
    const f16* pa[4];
#pragma unroll
    for (int mt = 0; mt < 4; ++mt) {
        int row = rbase + (mt << 6) + (w << 4) + lm;
        pa[mt] = rinter + (size_t)(slot0 + row) * MM + (lg << 3);
    }

    f32x4 acc[4][2] = {};

    DN_ISSUE(0,  Bd0)
    DN_ISSUE(64, Bd1)

    DN_PH(0, 2, Bd0, Bd2) DN_PH(1, 2, Bd1, Bd0) DN_PH(2, 2, Bd2, Bd1)
    DN_PH(3, 2, Bd0, Bd2) DN_PH(4, 2, Bd1, Bd0) DN_PH(5, 2, Bd2, Bd1)
    DN_PH(6, 2, Bd0, Bd0) DN_PH(7, 0, Bd1, Bd0)

#pragma unroll
    for (int mt = 0; mt < 4; ++mt) if (mact[mt])
#pragma unroll
        for (int fj = 0; fj < 2; ++fj)
#pragma unroll
            for (int rr = 0; rr < 4; ++rr) {
                int row = rbase + (mt << 6) + (w << 4) + (lg << 2) + rr;
                if (row < cnt) {
                    int t; float wt;
                    if (e < NE) { t = token_list[e * TT + row]; wt = weight_list[e * TT + row]; }
                    else        { t = row; wt = 1.f; }
                    atomicAdd(&out[(size_t)t * HH + n0 + (fj << 4) + lm], wt * acc[mt][fj][rr]);
                }
            }
}

extern "C" void kernel_launch(void* const* d_in, const int* in_sizes, int n_in,
                              void* d_out, int out_size, void* d_ws, size_t ws_size,
                              hipStream_t stream)
{
    const float* x       = (const float*)d_in[0];
    const float* gate_w  = (const float*)d_in[1];
    const float* w_gate  = (const float*)d_in[2];
    const float* w_up    = (const float*)d_in[3];
    const float* w_down  = (const float*)d_in[4];
    const float* ws_gate = (const float*)d_in[5];
    const float* ws_up   = (const float*)d_in[6];
    const float* ws_down = (const float*)d_in[7];
    float* out = (float*)d_out;

    // workspace: counts[16] | offs[17] | pad to 64 ints | token_list[16*1024] |
    // weight_list[16*1024] | rinter f16 [3072][512]
    int* counts = (int*)d_ws;
    int* offs = counts + 16;
    int* token_list = counts + 64;
    float* weight_list = (float*)(counts + 64 + NE * TT);
    f16* rinter = (f16*)(counts + 64 + 2 * NE * TT);

    hipMemsetAsync(counts, 0, 64, stream);
    hipMemsetAsync(out, 0, (size_t)TT * HH * sizeof(float), stream);
    router_k<<<dim3(TT / 4), 256, 0, stream>>>(x, gate_w, counts, token_list, weight_list);
    prefix_k<<<1, 64, 0, stream>>>(counts, offs);
    gu_k<<<dim3(MM / 32, 4, NE + 1), 256, 0, stream>>>(
        x, w_gate, w_up, ws_gate, ws_up, counts, offs, token_list, rinter);
    down_k<<<dim3(HH / 32, 4, NE + 1), 256, 0, stream>>>(
        rinter, w_down, ws_down, counts, offs, token_list, weight_list, out);
}

// Round 12
// 105.547 us; speedup vs baseline: 1.6726x; 1.6726x over previous
//
#include <hip/hip_runtime.h>
#include <math.h>

#define TT 1024   // tokens
#define HH 1024   // hidden
#define MM 512    // moe intermediate
#define NE 16     // routed experts (e == NE -> shared expert)
// TOP_K = 2, SCALE = 2.5, NORM_TOPK = true

typedef _Float16 f16;
typedef _Float16 f16x8 __attribute__((ext_vector_type(8)));
typedef float f32x4 __attribute__((ext_vector_type(4)));

// async global->LDS, 16B per lane, LDS dest = uniform base + lane*16 (linear).
#define GLL(g, l) __builtin_amdgcn_global_load_lds(                         \
    (const __attribute__((address_space(1))) void*)(g),                     \
    (__attribute__((address_space(3))) void*)(l), 16, 0, 0)

#define SB() __builtin_amdgcn_sched_barrier(0)
#define WAITVM(N) { SB(); asm volatile("s_waitcnt vmcnt(" #N ")"); SB(); }
#define BARRIER() __builtin_amdgcn_s_barrier()

// ---------------- router ----------------
__global__ __launch_bounds__(256) void router_k(
    const float* __restrict__ x, const float* __restrict__ gate_w,
    int* __restrict__ counts, int* __restrict__ token_list, float* __restrict__ weight_list)
{
    const int wave = threadIdx.x >> 6;
    const int lane = threadIdx.x & 63;
    const int t = (blockIdx.x << 2) + wave;
    const float* xr = x + (size_t)t * HH;
    float xv[16];
#pragma unroll
    for (int i = 0; i < 16; ++i) xv[i] = xr[lane + (i << 6)];
    float sc[NE];
#pragma unroll
    for (int e = 0; e < NE; ++e) {
        const float* gr = gate_w + e * HH;
        float acc = 0.f;
#pragma unroll
        for (int i = 0; i < 16; ++i) acc = fmaf(xv[i], gr[lane + (i << 6)], acc);
#pragma unroll
        for (int off = 32; off > 0; off >>= 1) acc += __shfl_down(acc, off, 64);
        sc[e] = acc;   // valid on lane 0
    }
    if (lane == 0) {
        float l1 = -1e30f, l2 = -1e30f; int i1 = 0, i2 = 0;
#pragma unroll
        for (int e = 0; e < NE; ++e) {
            float v = sc[e];
            if (v > l1) { l2 = l1; i2 = i1; l1 = v; i1 = e; }
            else if (v > l2) { l2 = v; i2 = e; }
        }
        float w1 = 1.f / (1.f + __expf(-l1));
        float w2 = 1.f / (1.f + __expf(-l2));
        const float inv = 2.5f / (w1 + w2 + 1e-20f);
        w1 *= inv; w2 *= inv;
        int s1 = atomicAdd(&counts[i1], 1);
        token_list[i1 * TT + s1] = t;
        weight_list[i1 * TT + s1] = w1;
        int s2 = atomicAdd(&counts[i2], 1);
        token_list[i2 * TT + s2] = t;
        weight_list[i2 * TT + s2] = w2;
    }
}

__global__ void prefix_k(const int* __restrict__ counts, int* __restrict__ offs)
{
    if (threadIdx.x == 0 && blockIdx.x == 0) {
        int acc = 0;
#pragma unroll
        for (int e = 0; e < NE; ++e) { offs[e] = acc; acc += counts[e]; }
        offs[NE] = acc;
    }
}

// ================= fused gate/up =================
// Round-10 kernel, ONE change: 1D flat grid with expert->XCD clustering.
// XCD = flat & 7. Per XCD q: experts {q, q+8} (256 tiles each: 16n x 16r)
// then a 32-tile slice of the shared expert. All surviving blocks of one
// expert share one XCD => their 128B panel reads union to dense 2KB rows
// in that XCD's L2 -> dense HBM stream.

#define GU_ISSUE(K0, AS, BG, BU) {                                          \
    _Pragma("unroll") for (int i = 0; i < 4; ++i)                           \
        GLL(pA[i] + (K0), &AS[aw + 4*i][0]);                                \
    _Pragma("unroll") for (int i = 0; i < 2; ++i) {                         \
        GLL(pBg[i] + (size_t)(K0) * MM, &BG[(w << 4) + 8*i][0]);            \
        GLL(pBu[i] + (size_t)(K0) * MM, &BU[(w << 4) + 8*i][0]); } }

#define GU_COMP(AS, BG, BU) {                                               \
    _Pragma("unroll") for (int h = 0; h < 2; ++h) {                         \
        const int kb = (h << 5) + (lg << 3);                                \
        const int xr = (lm & 7) << 2;                                       \
        f16x8 af[2];                                                        \
        _Pragma("unroll") for (int f = 0; f < 2; ++f) {                     \
            const int m = wm + (f << 4) + lm;                               \
            float4 lo = *(const float4*)&AS[m][kb ^ xr];                    \
            float4 hi = *(const float4*)&AS[m][(kb + 4) ^ xr];              \
            af[f] = (f16x8){(f16)lo.x,(f16)lo.y,(f16)lo.z,(f16)lo.w,        \
                            (f16)hi.x,(f16)hi.y,(f16)hi.z,(f16)hi.w};       \
        }                                                                   \
        const int bc = (wn + lm) ^ ((lg & 1) << 4);                         \
        f16x8 bg, bu;                                                       \
        _Pragma("unroll") for (int j = 0; j < 8; ++j) {                     \
            bg[j] = (f16)BG[kb + j][bc]; bu[j] = (f16)BU[kb + j][bc]; }     \
        _Pragma("unroll") for (int f = 0; f < 2; ++f) {                     \
            accg[f] = __builtin_amdgcn_mfma_f32_16x16x32_f16(af[f], bg, accg[f], 0, 0, 0); \
            accu[f] = __builtin_amdgcn_mfma_f32_16x16x32_f16(af[f], bu, accu[f], 0, 0, 0); } } }

__global__ __launch_bounds__(256) void gu_k(
    const float* __restrict__ x,
    const float* __restrict__ w_gate, const float* __restrict__ w_up,
    const float* __restrict__ ws_gate, const float* __restrict__ ws_up,
    const int* __restrict__ counts, const int* __restrict__ offs,
    const int* __restrict__ token_list, f16* __restrict__ rinter)
{
    // flat-id -> (expert, n-tile, row-tile) with XCD clustering
    const int F = blockIdx.x;
    const int Q = F & 7;
    const int J = F >> 3;           // 0..543
    int e, tile;
    if (J < 512) { e = Q + ((J >> 8) << 3); tile = J & 255; }
    else         { e = NE; tile = (Q << 5) + (J - 512); }
    const int n0 = (tile & 15) << 5;
    const int r0 = (tile >> 4) << 6;

    int cnt, slot0;
    const float *wgp, *wup;
    if (e < NE) {
        cnt = counts[e]; slot0 = offs[e];
        wgp = w_gate + (size_t)e * HH * MM;
        wup = w_up   + (size_t)e * HH * MM;
    } else {
        cnt = TT; slot0 = 2 * TT;
        wgp = ws_gate; wup = ws_up;
    }
    if (r0 >= cnt) return;

    __shared__ float As0[64][64], As1[64][64];
    __shared__ float Bg0[64][32], Bg1[64][32];
    __shared__ float Bu0[64][32], Bu1[64][32];
    __shared__ int toks[64];

    const int tid = threadIdx.x;
    if (tid < 64) {
        int i = r0 + tid; if (i >= cnt) i = cnt - 1;
        toks[tid] = (e < NE) ? token_list[e * TT + i] : i;
    }
    __syncthreads();

    const int w = tid >> 6, lane = tid & 63;
    const int lm = lane & 15, lg = lane >> 4;
    const int wm = (w >> 1) << 5, wn = (w & 1) << 4;
    const int aw = w << 4;                      // A staging row base (16 rows/wave)

    // per-lane global pointers (swizzle folded in; phase adds K0)
    const float* pA[4];
#pragma unroll
    for (int i = 0; i < 4; ++i) {
        int m = aw + 4*i + (lane >> 4);
        pA[i] = x + (size_t)toks[m] * HH + 4 * ((lane & 15) ^ (m & 7));
    }
    const float* pBg[2]; const float* pBu[2];
#pragma unroll
    for (int i = 0; i < 2; ++i) {
        int kr = (w << 4) + 8*i + (lane >> 3);
        int sg = 4 * ((lane & 7) ^ ((i & 1) << 2));
        pBg[i] = wgp + (size_t)kr * MM + n0 + sg;
        pBu[i] = wup + (size_t)kr * MM + n0 + sg;
    }

    f32x4 accg[2] = {}, accu[2] = {};

    GU_ISSUE(0, As0, Bg0, Bu0)
#pragma unroll 1
    for (int t = 0; t < 14; t += 2) {
        GU_ISSUE((t + 1) << 6, As1, Bg1, Bu1)
        WAITVM(8) BARRIER();
        GU_COMP(As0, Bg0, Bu0)
        BARRIER();
        GU_ISSUE((t + 2) << 6, As0, Bg0, Bu0)
        WAITVM(8) BARRIER();
        GU_COMP(As1, Bg1, Bu1)
        BARRIER();
    }
    GU_ISSUE(15 << 6, As1, Bg1, Bu1)
    WAITVM(8) BARRIER();
    GU_COMP(As0, Bg0, Bu0)          // tile 14
    BARRIER();
    WAITVM(0) BARRIER();
    GU_COMP(As1, Bg1, Bu1)          // tile 15

    // epilogue: silu(g)*u -> f16; C/D: col=lane&15, row=(lane>>4)*4+reg
#pragma unroll
    for (int fi = 0; fi < 2; ++fi)
#pragma unroll
        for (int rr = 0; rr < 4; ++rr) {
            const int m = wm + (fi << 4) + (lg << 2) + rr;
            if (r0 + m < cnt) {
                float g = accg[fi][rr], u = accu[fi][rr];
                float s = g / (1.f + __expf(-g));
                rinter[(size_t)(slot0 + r0 + m) * MM + n0 + wn + lm] = (f16)(s * u);
            }
        }
}

// ================= down: out[token] += weight * (rinter @ Wd) =================
// Same XCD clustering: per XCD q: experts {q, q+8} (512 tiles: 32n x 16r),
// then a 64-tile slice of the shared expert.

#define DN_ISSUE(K0, AS, BS) {                                              \
    _Pragma("unroll") for (int i = 0; i < 2; ++i) {                         \
        GLL(pa[i] + (K0), &AS[(w << 4) + 8*i][0]);                          \
        GLL(pb[i] + (size_t)(K0) * HH, &BS[(w << 4) + 8*i][0]); } }

#define DN_COMP(AS, BS) {                                                   \
    _Pragma("unroll") for (int h = 0; h < 2; ++h) {                         \
        const int kb = (h << 5) + (lg << 3);                                \
        const int xr = (lm & 7) << 3;                                       \
        f16x8 af[2];                                                        \
        _Pragma("unroll") for (int f = 0; f < 2; ++f)                       \
            af[f] = *(const f16x8*)&AS[wm + (f << 4) + lm][kb ^ xr];        \
        const int bc = (wn + lm) ^ ((lg & 1) << 4);                         \
        f16x8 bv;                                                           \
        _Pragma("unroll") for (int j = 0; j < 8; ++j) bv[j] = (f16)BS[kb + j][bc]; \
        _Pragma("unroll") for (int f = 0; f < 2; ++f)                       \
            acc[f] = __builtin_amdgcn_mfma_f32_16x16x32_f16(af[f], bv, acc[f], 0, 0, 0); } }

__global__ __launch_bounds__(256) void down_k(
    const f16* __restrict__ rinter,
    const float* __restrict__ w_down, const float* __restrict__ ws_down,
    const int* __restrict__ counts, const int* __restrict__ offs,
    const int* __restrict__ token_list, const float* __restrict__ weight_list,
    float* __restrict__ out)
{
    const int F = blockIdx.x;
    const int Q = F & 7;
    const int J = F >> 3;           // 0..1087
    int e, tile;
    if (J < 1024) { e = Q + ((J >> 9) << 3); tile = J & 511; }
    else          { e = NE; tile = (Q << 6) + (J - 1024); }
    const int n0 = (tile & 31) << 5;   // of HH
    const int r0 = (tile >> 5) << 6;

    int cnt, slot0; const float* wdp;
    if (e < NE) { cnt = counts[e]; slot0 = offs[e]; wdp = w_down + (size_t)e * MM * HH; }
    else        { cnt = TT; slot0 = 2 * TT; wdp = ws_down; }
    if (r0 >= cnt) return;

    __shared__ f16  As0[64][64], As1[64][64];
    __shared__ float Bs0[64][32], Bs1[64][32];

    const int tid = threadIdx.x;
    const int w = tid >> 6, lane = tid & 63;
    const int lm = lane & 15, lg = lane >> 4;
    const int wm = (w >> 1) << 5, wn = (w & 1) << 4;

    const f16* pa[2]; const float* pb[2];
#pragma unroll
    for (int i = 0; i < 2; ++i) {
        int m = (w << 4) + 8*i + (lane >> 3);       // A row (slots are contiguous)
        pa[i] = rinter + (size_t)(slot0 + r0 + m) * MM + 8 * ((lane & 7) ^ (m & 7));
        int kr = (w << 4) + 8*i + (lane >> 3);      // B k-row
        pb[i] = wdp + (size_t)kr * HH + n0 + 4 * ((lane & 7) ^ ((i & 1) << 2));
    }

    f32x4 acc[2] = {};

    DN_ISSUE(0, As0, Bs0)
#pragma unroll 1
    for (int t = 0; t < 6; t += 2) {
        DN_ISSUE((t + 1) << 6, As1, Bs1)
        WAITVM(4) BARRIER();
        DN_COMP(As0, Bs0)
        BARRIER();
        DN_ISSUE((t + 2) << 6, As0, Bs0)
        WAITVM(4) BARRIER();
        DN_COMP(As1, Bs1)
        BARRIER();
    }
    DN_ISSUE(7 << 6, As1, Bs1)
    WAITVM(4) BARRIER();
    DN_COMP(As0, Bs0)               // tile 6
    BARRIER();
    WAITVM(0) BARRIER();
    DN_COMP(As1, Bs1)               // tile 7

#pragma unroll
    for (int fi = 0; fi < 2; ++fi)
#pragma unroll
        for (int rr = 0; rr < 4; ++rr) {
            const int m = wm + (fi << 4) + (lg << 2) + rr;
            const int row = r0 + m;
            if (row < cnt) {
                int t; float wt;
                if (e < NE) { t = token_list[e * TT + row]; wt = weight_list[e * TT + row]; }
                else        { t = row; wt = 1.f; }
                atomicAdd(&out[(size_t)t * HH + n0 + wn + lm], wt * acc[fi][rr]);
            }
        }
}

extern "C" void kernel_launch(void* const* d_in, const int* in_sizes, int n_in,
                              void* d_out, int out_size, void* d_ws, size_t ws_size,
                              hipStream_t stream)
{
    const float* x       = (const float*)d_in[0];
    const float* gate_w  = (const float*)d_in[1];
    const float* w_gate  = (const float*)d_in[2];
    const float* w_up    = (const float*)d_in[3];
    const float* w_down  = (const float*)d_in[4];
    const float* ws_gate = (const float*)d_in[5];
    const float* ws_up   = (const float*)d_in[6];
    const float* ws_down = (const float*)d_in[7];
    float* out = (float*)d_out;

    // workspace: counts[16] | offs[17] | pad to 64 ints | token_list[16*1024] |
    // weight_list[16*1024] | rinter f16 [3072][512]
    int* counts = (int*)d_ws;
    int* offs = counts + 16;
    int* token_list = counts + 64;
    float* weight_list = (float*)(counts + 64 + NE * TT);
    f16* rinter = (f16*)(counts + 64 + 2 * NE * TT);

    hipMemsetAsync(counts, 0, 64, stream);
    hipMemsetAsync(out, 0, (size_t)TT * HH * sizeof(float), stream);
    router_k<<<dim3(TT / 4), 256, 0, stream>>>(x, gate_w, counts, token_list, weight_list);
    prefix_k<<<1, 64, 0, stream>>>(counts, offs);
    // 1D flat grids, expert->XCD clustered (XCD = id & 7)
    gu_k<<<dim3(8 * 544), 256, 0, stream>>>(
        x, w_gate, w_up, ws_gate, ws_up, counts, offs, token_list, rinter);
    down_k<<<dim3(8 * 1088), 256, 0, stream>>>(
        rinter, w_down, ws_down, counts, offs, token_list, weight_list, out);
}